// Round 8
// baseline (613.661 us; speedup 1.0000x reference)
//
#include <hip/hip_runtime.h>
#include <math.h>

#define T_TOTAL 16384   // B*S
#define C_DIM   4096
#define E_DIM   64
#define K_TOP   8
#define S_SEQ   4096
#define B_BATCH 4
#define BK      128     // channels per LDS tile
#define NT      (C_DIM / BK)   // 32 tiles

// ---- kernel 0: pack W [E][C] -> wp[c4][e] = float4(W[e][4c4..4c4+3]) ----
// Consecutive lanes (e) then read consecutive float4s: 1KB coalesced/instr.
__global__ void pack_w_kernel(const float* __restrict__ w,
                              float4* __restrict__ wp) {
    int g  = blockIdx.x * 256 + threadIdx.x;   // 0 .. C/4*E-1
    int e  = g & (E_DIM - 1);
    int c4 = g >> 6;
    float4 v = *reinterpret_cast<const float4*>(w + (size_t)e * C_DIM + (size_t)c4 * 4);
    wp[(size_t)c4 * E_DIM + e] = v;
}

// ---- kernel 1: fully fused gate ----
// Grid 256 x 256 threads. Wave wv owns tokens [blk*64 + wv*16, +16); lane =
// expert. Per BK=128 tile: wave stages its private 16x128 x-tile into LDS
// (coalesced float4, register-prefetched one tile ahead); consumes via
// ds_read_b128 broadcast; W stationary 32 ch at a time in VGPRs from the
// packed wp (coalesced, L1/L2-hot). No barriers (wave-private LDS regions).
// Numerics: per-(token,expert) ascending-channel serial chains flushed every
// 256 ch (2 tiles) — identical grouping to the r5-r7 verified chains.
// Epilogue: logits already in lane=expert layout -> verified top-8 butterfly.
__global__ __launch_bounds__(256, 4)
void gate_fused_kernel(const float* __restrict__ x,
                       const float4* __restrict__ wp,
                       const float* __restrict__ expert_bias,
                       float* __restrict__ out,
                       float* __restrict__ facc,
                       float* __restrict__ pacc) {
    const int lane = threadIdx.x & 63;                        // expert
    const int wv   = __builtin_amdgcn_readfirstlane(threadIdx.x >> 6);
    const int tok0 = blockIdx.x * 64 + wv * 16;               // wave's tokens

    __shared__ float4 xs[4][16][BK / 4];                      // 32 KB, per-wave

    // staging pattern: pair i covers rows 2i+sr (sr = lane>>5), c4 slot sc
    const int sr = lane >> 5;
    const int sc = lane & 31;
    const float4* xsrc = reinterpret_cast<const float4*>(
        x + (size_t)(tok0 + sr) * C_DIM) + sc;
    // tile kt, pair i: xsrc[i*2048 + kt*32]  (row stride 1024 float4)

    float4 xf[8];
#pragma unroll
    for (int i = 0; i < 8; ++i)                               // prologue: tile 0
        xf[i] = xsrc[(size_t)i * 2048];

    float accO[16], accI[16];
#pragma unroll
    for (int t = 0; t < 16; ++t) { accO[t] = 0.0f; accI[t] = 0.0f; }

#pragma unroll 1
    for (int kt = 0; kt < NT; ++kt) {
        // commit current tile to this wave's LDS region
#pragma unroll
        for (int i = 0; i < 8; ++i)
            xs[wv][2 * i + sr][sc] = xf[i];
        // prefetch next tile (in flight across the whole compute phase)
        if (kt < NT - 1) {
#pragma unroll
            for (int i = 0; i < 8; ++i)
                xf[i] = xsrc[(size_t)i * 2048 + (size_t)(kt + 1) * 32];
        }

        // compute: 4 passes of 32 channels
#pragma unroll 1
        for (int p = 0; p < 4; ++p) {
            float4 w4[8];                                     // lane's expert, 32 ch
#pragma unroll
            for (int j = 0; j < 8; ++j)
                w4[j] = wp[(size_t)(kt * 32 + p * 8 + j) * E_DIM + lane];
#pragma unroll
            for (int t = 0; t < 16; ++t) {
                float a = accI[t];
#pragma unroll
                for (int j = 0; j < 8; ++j) {                 // ascending channels
                    const float4 xv = xs[wv][t][p * 8 + j];   // broadcast read
                    a = fmaf(xv.x, w4[j].x, a);
                    a = fmaf(xv.y, w4[j].y, a);
                    a = fmaf(xv.z, w4[j].z, a);
                    a = fmaf(xv.w, w4[j].w, a);
                }
                accI[t] = a;
            }
        }
        if ((kt & 1) == 1) {                                  // 256-ch flush
#pragma unroll
            for (int t = 0; t < 16; ++t) { accO[t] += accI[t]; accI[t] = 0.0f; }
        }
    }

    // ---- fused epilogue: verified top-8 butterfly (lane = expert) ----
    const float be = expert_bias[lane];
    const int   b  = tok0 / S_SEQ;                            // uniform
    float f_local = 0.0f, p_local = 0.0f;

    for (int m = 0; m < 16; ++m) {
        const int tk = tok0 + m;
        const float logit = accO[m];
        const float sc2 = 1.0f / (1.0f + expf(-logit));       // sigmoid
        float ssum = sc2;
#pragma unroll
        for (int off = 32; off >= 1; off >>= 1) ssum += __shfl_xor(ssum, off, 64);
        p_local += sc2 / (ssum + 1e-10f);

        // top-8 over biased logits (descending, lowest-index tie-break)
        float v = logit + be;
        float wsum = 0.0f, my_w = 0.0f;
        int   my_i = 0;
#pragma unroll
        for (int k = 0; k < K_TOP; ++k) {
            float rv = v;
            int   ri = lane;
#pragma unroll
            for (int off = 32; off >= 1; off >>= 1) {
                float ov = __shfl_xor(rv, off, 64);
                int   oi = __shfl_xor(ri, off, 64);
                if (ov > rv || (ov == rv && oi < ri)) { rv = ov; ri = oi; }
            }
            float wsc = __shfl(sc2, ri, 64);                  // winner's score
            wsum += wsc;
            if (lane == k)  { my_i = ri; my_w = wsc; }
            if (lane == ri) { v = -INFINITY; f_local += 1.0f; }
        }
        if (lane < K_TOP) {
            out[(size_t)tk * K_TOP + lane] = (float)my_i;
            out[(size_t)T_TOTAL * K_TOP + (size_t)tk * K_TOP + lane] =
                my_w / (wsum + 1e-10f);
        }
    }

    atomicAdd(&facc[b * E_DIM + lane], f_local);
    atomicAdd(&pacc[b * E_DIM + lane], p_local);
}

// ---- tiny loss reduction: 4x64 f*p -> scalar ----
__global__ void loss_kernel(const float* __restrict__ facc,
                            const float* __restrict__ pacc,
                            float* __restrict__ out_loss) {
    const int tid = threadIdx.x;                 // 256 threads = B*E
    float f = facc[tid] * (1.0f / ((float)K_TOP * (float)S_SEQ));
    float p = pacc[tid] * (1.0f / (float)S_SEQ);
    float v = f * p;
#pragma unroll
    for (int off = 32; off >= 1; off >>= 1) v += __shfl_xor(v, off, 64);
    __shared__ float sred[4];
    if ((tid & 63) == 0) sred[tid >> 6] = v;
    __syncthreads();
    if (tid == 0) {
        float tot = sred[0] + sred[1] + sred[2] + sred[3];
        out_loss[0] = 0.001f * tot / (float)B_BATCH;
    }
}

extern "C" void kernel_launch(void* const* d_in, const int* in_sizes, int n_in,
                              void* d_out, int out_size, void* d_ws, size_t ws_size,
                              hipStream_t stream) {
    const float* x    = (const float*)d_in[0];   // [4,4096,4096] f32
    const float* w    = (const float*)d_in[1];   // [64,4096] f32
    const float* bias = (const float*)d_in[2];   // [64] f32
    float* out = (float*)d_out;                  // [131072 idx][131072 w][1 loss]

    float*  facc = (float*)d_ws;                 // 256 floats
    float*  pacc = facc + B_BATCH * E_DIM;       // 256 floats
    float4* wpck = (float4*)((char*)d_ws + 4096);// 1 MB packed W

    // zero the f/p accumulators every call (atomics accumulate)
    hipMemsetAsync(d_ws, 0, 2048, stream);

    pack_w_kernel<<<(C_DIM / 4 * E_DIM) / 256, 256, 0, stream>>>(w, wpck);

    gate_fused_kernel<<<T_TOTAL / 64, 256, 0, stream>>>(
        x, wpck, bias, out, facc, pacc);

    loss_kernel<<<1, 256, 0, stream>>>(facc, pacc, out + 2 * (size_t)T_TOTAL * K_TOP);
}

// Round 9
// 419.742 us; speedup vs baseline: 1.4620x; 1.4620x over previous
//
#include <hip/hip_runtime.h>
#include <math.h>

#define T_TOTAL 16384   // B*S
#define C_DIM   4096
#define E_DIM   64
#define K_TOP   8
#define S_SEQ   4096
#define B_BATCH 4
#define NKQ     8       // K splits
#define KQ_LEN  512     // channels per split
#define BK      32      // channels per LDS tile
#define NTILE   16      // KQ_LEN / BK
#define TOK_BLK 128     // tokens per block

// ---- pack W: wp2[c4][j*4+eg] = float4 of W[eg*16+j][4c4..+4] ----
// gemv instr j then reads 4 consecutive float4 (eg=0..3) = one 64B line.
__global__ void pack_w_kernel(const float* __restrict__ w,
                              float4* __restrict__ wp2) {
    int g = blockIdx.x * 256 + threadIdx.x;    // [0, 1024*64)
    int c4 = g >> 6, slot = g & 63;
    int e = (slot & 3) * 16 + (slot >> 2);     // eg*16 + j
    wp2[g] = *reinterpret_cast<const float4*>(w + (size_t)e * C_DIM + c4 * 4);
}

// ---- kernel 1: partial GEMV, 2D register tile (2 tokens x 16 experts) ----
// grid 1024: tg = b&127 (128 tokens), kq = b>>7 (512-ch split).
// lane = (tl = lane&15 token-lane, eg = lane>>4 expert-group).
// Wave wv owns tokens wv*32 + tl + 16r (r<2), experts eg*16 + j (j<16).
// x: reg-staged LDS tiles (BK=32, dbuf, pad-9 rows), ds_read_b128 broadcast
//    feeds 128 fma each. W: packed wp2, 64B-line broadcast loads, L1-hot.
// Numerics: ascending-channel fmaf chains, accI flushed every 256 ch.
__global__ __launch_bounds__(256, 4)
void gemv8_kernel(const float* __restrict__ x,
                  const float4* __restrict__ wp2,
                  float* __restrict__ part) {
    const int tid  = threadIdx.x;
    const int lane = tid & 63;
    const int wv   = tid >> 6;
    const int tl   = lane & 15;
    const int eg   = lane >> 4;
    const int tg   = blockIdx.x & 127;
    const int kq   = blockIdx.x >> 7;
    const int tok0 = tg * TOK_BLK;

    __shared__ float4 xs[2][TOK_BLK][9];       // pad 8->9: 2-way read conflicts

    // staging map: thread -> (token stok + 32rr, slot ss); 128B/token contiguous
    const int stok = tid >> 3;                 // 0..31
    const int ss   = tid & 7;
    const float* xsrc = x + (size_t)(tok0 + stok) * C_DIM + kq * KQ_LEN + ss * 4;

    float4 xf0, xf1, xf2, xf3;
    xf0 = *reinterpret_cast<const float4*>(xsrc);
    xf1 = *reinterpret_cast<const float4*>(xsrc + 32 * C_DIM);
    xf2 = *reinterpret_cast<const float4*>(xsrc + 64 * C_DIM);
    xf3 = *reinterpret_cast<const float4*>(xsrc + 96 * C_DIM);
    xs[0][stok][ss]      = xf0;
    xs[0][stok + 32][ss] = xf1;
    xs[0][stok + 64][ss] = xf2;
    xs[0][stok + 96][ss] = xf3;
    __syncthreads();

    float accO[2][16], accI[2][16];
#pragma unroll
    for (int j = 0; j < 16; ++j) {
        accO[0][j] = 0.0f; accO[1][j] = 0.0f;
        accI[0][j] = 0.0f; accI[1][j] = 0.0f;
    }

    const int trow0 = wv * 32 + tl;
    const int trow1 = trow0 + 16;

    for (int t = 0; t < NTILE; ++t) {
        if (t + 1 < NTILE) {                   // prefetch next tile into regs
            const float* xn = xsrc + (t + 1) * BK;
            xf0 = *reinterpret_cast<const float4*>(xn);
            xf1 = *reinterpret_cast<const float4*>(xn + 32 * C_DIM);
            xf2 = *reinterpret_cast<const float4*>(xn + 64 * C_DIM);
            xf3 = *reinterpret_cast<const float4*>(xn + 96 * C_DIM);
        }
        const int cur = t & 1;

#pragma unroll 1
        for (int c4 = 0; c4 < 8; ++c4) {
            const float4 xv0 = xs[cur][trow0][c4];
            const float4 xv1 = xs[cur][trow1][c4];
            const float4* wrow =
                wp2 + (((size_t)(kq * (KQ_LEN / 4) + t * 8 + c4)) << 6) + eg;
#pragma unroll
            for (int jh = 0; jh < 4; ++jh) {
                float4 w4[4];
#pragma unroll
                for (int jj = 0; jj < 4; ++jj)
                    w4[jj] = wrow[(jh * 4 + jj) * 4];   // one 64B line/instr
#pragma unroll
                for (int jj = 0; jj < 4; ++jj) {
                    const int j = jh * 4 + jj;
                    float a0 = accI[0][j], a1 = accI[1][j];
                    a0 = fmaf(xv0.x, w4[jj].x, a0);
                    a0 = fmaf(xv0.y, w4[jj].y, a0);
                    a0 = fmaf(xv0.z, w4[jj].z, a0);
                    a0 = fmaf(xv0.w, w4[jj].w, a0);
                    a1 = fmaf(xv1.x, w4[jj].x, a1);
                    a1 = fmaf(xv1.y, w4[jj].y, a1);
                    a1 = fmaf(xv1.z, w4[jj].z, a1);
                    a1 = fmaf(xv1.w, w4[jj].w, a1);
                    accI[0][j] = a0; accI[1][j] = a1;
                }
            }
        }
        if ((t & 7) == 7) {                    // flush every 256 channels
#pragma unroll
            for (int j = 0; j < 16; ++j) {
                accO[0][j] += accI[0][j]; accI[0][j] = 0.0f;
                accO[1][j] += accI[1][j]; accI[1][j] = 0.0f;
            }
        }
        if (t + 1 < NTILE) {                   // commit prefetch to other buf
            const int nxt = cur ^ 1;
            xs[nxt][stok][ss]      = xf0;
            xs[nxt][stok + 32][ss] = xf1;
            xs[nxt][stok + 64][ss] = xf2;
            xs[nxt][stok + 96][ss] = xf3;
        }
        __syncthreads();                       // single barrier per tile
    }

    // store partials: part[kq][tok][e]; 16 consecutive experts per lane
#pragma unroll
    for (int r = 0; r < 2; ++r) {
        float* pb = part + ((size_t)kq * T_TOTAL + tok0 + wv * 32 + tl + 16 * r)
                            * E_DIM + eg * 16;
#pragma unroll
        for (int q = 0; q < 4; ++q)
            *reinterpret_cast<float4*>(pb + 4 * q) =
                make_float4(accO[r][4 * q], accO[r][4 * q + 1],
                            accO[r][4 * q + 2], accO[r][4 * q + 3]);
    }
}

// ---- kernel 2: reduce 8 splits + sigmoid + top-8 + f/p partials ----
__global__ __launch_bounds__(256, 4)
void topk_kernel(const float* __restrict__ part,
                 const float* __restrict__ expert_bias,
                 float* __restrict__ out,
                 float* __restrict__ facc,
                 float* __restrict__ pacc) {
    const int lane = threadIdx.x & 63;
    const int wv   = threadIdx.x >> 6;
    const int tok0 = blockIdx.x * 64;

    __shared__ float slog[64][65];

    const int tt  = lane >> 2;
    const int s   = lane & 3;
    const int tl  = wv * 16 + tt;          // token-in-block
    const int tok = tok0 + tl;

    float4 sum4[4];
#pragma unroll
    for (int i = 0; i < 4; ++i) sum4[i] = make_float4(0.f, 0.f, 0.f, 0.f);
#pragma unroll
    for (int kq = 0; kq < NKQ; ++kq) {     // serial split sum (deterministic)
        const float4* pp = reinterpret_cast<const float4*>(
            part + ((size_t)kq * T_TOTAL + tok) * E_DIM + 16 * s);
#pragma unroll
        for (int i = 0; i < 4; ++i) {
            float4 v = pp[i];
            sum4[i].x += v.x; sum4[i].y += v.y;
            sum4[i].z += v.z; sum4[i].w += v.w;
        }
    }
#pragma unroll
    for (int i = 0; i < 4; ++i) {
        slog[tl][16 * s + 4 * i + 0] = sum4[i].x;
        slog[tl][16 * s + 4 * i + 1] = sum4[i].y;
        slog[tl][16 * s + 4 * i + 2] = sum4[i].z;
        slog[tl][16 * s + 4 * i + 3] = sum4[i].w;
    }
    __syncthreads();

    // ---- phase B: lane = expert; wave wv handles tokens wv*16 .. wv*16+15
    const float be = expert_bias[lane];
    const int   b  = tok0 / S_SEQ;         // uniform per block
    float f_local = 0.0f, p_local = 0.0f;

    for (int m = 0; m < 16; ++m) {
        const int tl2 = wv * 16 + m;
        const int tk  = tok0 + tl2;
        const float logit = slog[tl2][lane];
        const float sc = 1.0f / (1.0f + expf(-logit));   // sigmoid
        float ssum = sc;
#pragma unroll
        for (int off = 32; off >= 1; off >>= 1) ssum += __shfl_xor(ssum, off, 64);
        p_local += sc / (ssum + 1e-10f);

        // top-8 over biased logits (descending, lowest-index tie-break)
        float v = logit + be;
        float wsum = 0.0f, my_w = 0.0f;
        int   my_i = 0;
#pragma unroll
        for (int k = 0; k < K_TOP; ++k) {
            float rv = v;
            int   ri = lane;
#pragma unroll
            for (int off = 32; off >= 1; off >>= 1) {
                float ov = __shfl_xor(rv, off, 64);
                int   oi = __shfl_xor(ri, off, 64);
                if (ov > rv || (ov == rv && oi < ri)) { rv = ov; ri = oi; }
            }
            float wsc = __shfl(sc, ri, 64);   // winner's score (uniform)
            wsum += wsc;
            if (lane == k)  { my_i = ri; my_w = wsc; }
            if (lane == ri) { v = -INFINITY; f_local += 1.0f; }
        }
        if (lane < K_TOP) {
            out[(size_t)tk * K_TOP + lane] = (float)my_i;
            out[(size_t)T_TOTAL * K_TOP + (size_t)tk * K_TOP + lane] =
                my_w / (wsum + 1e-10f);
        }
    }

    atomicAdd(&facc[b * E_DIM + lane], f_local);
    atomicAdd(&pacc[b * E_DIM + lane], p_local);
}

// ---- tiny loss reduction: 4x64 f*p -> scalar ----
__global__ void loss_kernel(const float* __restrict__ facc,
                            const float* __restrict__ pacc,
                            float* __restrict__ out_loss) {
    const int tid = threadIdx.x;                 // 256 threads = B*E
    float f = facc[tid] * (1.0f / ((float)K_TOP * (float)S_SEQ));
    float p = pacc[tid] * (1.0f / (float)S_SEQ);
    float v = f * p;
#pragma unroll
    for (int off = 32; off >= 1; off >>= 1) v += __shfl_xor(v, off, 64);
    __shared__ float sred[4];
    if ((tid & 63) == 0) sred[tid >> 6] = v;
    __syncthreads();
    if (tid == 0) {
        float tot = sred[0] + sred[1] + sred[2] + sred[3];
        out_loss[0] = 0.001f * tot / (float)B_BATCH;
    }
}

extern "C" void kernel_launch(void* const* d_in, const int* in_sizes, int n_in,
                              void* d_out, int out_size, void* d_ws, size_t ws_size,
                              hipStream_t stream) {
    const float* x    = (const float*)d_in[0];   // [4,4096,4096] f32
    const float* w    = (const float*)d_in[1];   // [64,4096] f32
    const float* bias = (const float*)d_in[2];   // [64] f32
    float* out = (float*)d_out;                  // [131072 idx][131072 w][1 loss]

    float*  facc = (float*)d_ws;                 // 256 floats
    float*  pacc = facc + B_BATCH * E_DIM;       // 256 floats
    float4* wp2  = (float4*)((char*)d_ws + 4096);              // 1 MB packed W
    float*  part = (float*)((char*)d_ws + 4096 + (1 << 20));   // 32 MB partials

    // zero the f/p accumulators every call (atomics accumulate)
    hipMemsetAsync(d_ws, 0, 2048, stream);

    pack_w_kernel<<<256, 256, 0, stream>>>(w, wp2);

    gemv8_kernel<<<TOK_BLK * NKQ, 256, 0, stream>>>(x, wp2, part);

    topk_kernel<<<T_TOTAL / 64, 256, 0, stream>>>(part, bias, out, facc, pacc);

    loss_kernel<<<1, 256, 0, stream>>>(facc, pacc, out + 2 * (size_t)T_TOTAL * K_TOP);
}